// Round 1
// baseline (420.178 us; speedup 1.0000x reference)
//
#include <hip/hip_runtime.h>
#include <cstdint>
#include <cstddef>

// Problem constants (N=2, C=128, Ce=64, H=W=96)
#define HW_ 9216
#define CC 128
#define CE 64
#define NQT 144      // HW/64 Q-tiles
#define NCHUNK 2
#define CHUNKJ 4608  // HW/NCHUNK
#define LOG2E 1.44269504088896f

typedef short bf16x8 __attribute__((ext_vector_type(8)));
typedef float f32x4 __attribute__((ext_vector_type(4)));

__device__ __forceinline__ unsigned short f2bf(float f) {
    unsigned int u = __builtin_bit_cast(unsigned int, f);
    u += 0x7FFFu + ((u >> 16) & 1u);   // RNE
    return (unsigned short)(u >> 16);
}

// ---------------------------------------------------------------------------
// Kernel 1: transpose weights into wt[c][o], o in [0,256): 0..63=w1, 64..127=w2,
// 128..255=wa.  Gives the conv kernel contiguous per-c weight rows (s_load).
// ---------------------------------------------------------------------------
__global__ __launch_bounds__(256) void prep_w(const float* __restrict__ w1,
                                              const float* __restrict__ w2,
                                              const float* __restrict__ wa,
                                              float* __restrict__ wt) {
    int idx = blockIdx.x * 256 + threadIdx.x;   // 32768 total
    int o = idx >> 7, c = idx & 127;
    float v;
    if (o < 64)       v = w1[o * 128 + c];
    else if (o < 128) v = w2[(o - 64) * 128 + c];
    else              v = wa[(o - 128) * 128 + c];
    wt[c * 256 + o] = v;
}

// ---------------------------------------------------------------------------
// Kernel 2: 1x1 conv + PReLU (fp32 accumulate), write bf16:
//   oset 0 -> Q[n][p][d]  (= e1[n][d][p])
//   oset 1 -> K[n][p][d]  (= e2[n][d][p])
//   oset 2,3 -> Vt[n][c][p] (= xa[n][c][p])
// ---------------------------------------------------------------------------
__global__ __launch_bounds__(256) void conv_kernel(
    const float* __restrict__ x, const float* __restrict__ wt,
    const float* __restrict__ b1, const float* __restrict__ a1,
    const float* __restrict__ b2, const float* __restrict__ a2,
    const float* __restrict__ ba, const float* __restrict__ aa,
    unsigned short* __restrict__ qb, unsigned short* __restrict__ kb,
    unsigned short* __restrict__ vtb) {
    const int ptile = blockIdx.x;   // 144
    const int oset  = blockIdx.y;   // 4
    const int n     = blockIdx.z;   // 2
    const int t = threadIdx.x;
    const int p = t & 63;
    const int og = __builtin_amdgcn_readfirstlane(t >> 6);   // wave id, uniform
    const int p0 = ptile * 64;

    __shared__ float xs[128 * 64];
    for (int c = t >> 6; c < 128; c += 4)
        xs[c * 64 + p] = x[((size_t)n * CC + c) * HW_ + p0 + p];
    __syncthreads();

    const int obase = oset * 64 + og * 16;   // global o in [0,256)
    float acc[16];
#pragma unroll
    for (int i = 0; i < 16; i++) acc[i] = 0.f;

    for (int c = 0; c < 128; c++) {
        float xv = xs[c * 64 + p];
        const float* wr = wt + c * 256 + obase;   // uniform -> s_load
#pragma unroll
        for (int i = 0; i < 16; i++) acc[i] = fmaf(wr[i], xv, acc[i]);
    }

    const float* bias_p;
    const float* slope_p;
    if (oset == 0)      { bias_p = b1; slope_p = a1; }
    else if (oset == 1) { bias_p = b2; slope_p = a2; }
    else                { bias_p = ba; slope_p = aa; }
    const float slope = slope_p[0];

    unsigned short vals[16];
#pragma unroll
    for (int i = 0; i < 16; i++) {
        float bv = (oset < 2) ? bias_p[og * 16 + i] : bias_p[obase - 128 + i];
        float y = acc[i] + bv;
        y = (y >= 0.f) ? y : slope * y;
        vals[i] = f2bf(y);
    }

    if (oset < 2) {
        unsigned short* dst = (oset == 0 ? qb : kb) + ((size_t)n * HW_ + p0 + p) * 64 + og * 16;
        bf16x8 v0, v1;
#pragma unroll
        for (int i = 0; i < 8; i++) { v0[i] = (short)vals[i]; v1[i] = (short)vals[8 + i]; }
        *(bf16x8*)(dst)     = v0;
        *(bf16x8*)(dst + 8) = v1;
    } else {
        int c0 = obase - 128;
#pragma unroll
        for (int i = 0; i < 16; i++)
            vtb[((size_t)n * CC + c0 + i) * HW_ + p0 + p] = vals[i];
    }
}

// ---------------------------------------------------------------------------
// Kernel 3: flash attention, bf16 MFMA 16x16x32.
// Block = 256 thr (4 waves). Q-tile = 64 rows (wave w owns rows w*16..+16).
// KV split into NCHUNK chunks across blockIdx.y; partial (O', m, l) to ws.
// LDS tiles use XOR swizzle at 8-element (16B) granularity: chunk' = cs ^ (row&7).
// ---------------------------------------------------------------------------
__global__ __launch_bounds__(256) void attn_kernel(
    const unsigned short* __restrict__ qb, const unsigned short* __restrict__ kb,
    const unsigned short* __restrict__ vtb,
    float* __restrict__ o_part, float* __restrict__ ml_part) {
    const int qt    = blockIdx.x;   // 144
    const int chunk = blockIdx.y;   // 2
    const int n     = blockIdx.z;   // 2
    const int t = threadIdx.x;
    const int w = t >> 6;
    const int lane = t & 63;
    const int l15 = lane & 15;
    const int quad = lane >> 4;

    __shared__ __align__(16) unsigned short k_lds[64 * 64];    // [j][d]
    __shared__ __align__(16) unsigned short v_lds[128 * 64];   // [c][j]
    __shared__ __align__(16) unsigned short p_lds[4 * 16 * 64]; // per-wave [row][j]

    // Q A-fragments (row = lane&15, k = quad*8.. contiguous): one 16B load each
    const int row_g = qt * 64 + w * 16 + l15;
    const bf16x8 aq0 = *(const bf16x8*)(qb + ((size_t)n * HW_ + row_g) * 64 + quad * 8);
    const bf16x8 aq1 = *(const bf16x8*)(qb + ((size_t)n * HW_ + row_g) * 64 + 32 + quad * 8);

    f32x4 acc_o[8];
#pragma unroll
    for (int i = 0; i < 8; i++) acc_o[i] = (f32x4){0.f, 0.f, 0.f, 0.f};
    float m_r[4], l_r[4];
#pragma unroll
    for (int r = 0; r < 4; r++) { m_r[r] = -INFINITY; l_r[r] = 0.f; }

    const int j0_base = chunk * CHUNKJ;
    const int stg_row = t >> 3, stg_seg = t & 7;

    for (int it = 0; it < CHUNKJ / 64; ++it) {
        const int j0 = j0_base + it * 64;
        __syncthreads();   // previous iteration's LDS reads done
        // stage K tile (64x64 bf16) and Vt tile (128x64 bf16)
#pragma unroll
        for (int rep = 0; rep < 2; rep++) {
            int r = stg_row + rep * 32;
            bf16x8 val = *(const bf16x8*)(kb + ((size_t)n * HW_ + j0 + r) * 64 + stg_seg * 8);
            *(bf16x8*)&k_lds[r * 64 + ((stg_seg ^ (r & 7)) * 8)] = val;
        }
#pragma unroll
        for (int rep = 0; rep < 4; rep++) {
            int r = stg_row + rep * 32;
            bf16x8 val = *(const bf16x8*)(vtb + ((size_t)n * CC + r) * HW_ + j0 + stg_seg * 8);
            *(bf16x8*)&v_lds[r * 64 + ((stg_seg ^ (r & 7)) * 8)] = val;
        }
        __syncthreads();

        // S = Q K^T : wave's 16 rows x 64 cols
        f32x4 s[4];
#pragma unroll
        for (int ct = 0; ct < 4; ct++) {
            int krow = ct * 16 + l15;
            bf16x8 bk0 = *(const bf16x8*)&k_lds[krow * 64 + (((quad) ^ (l15 & 7)) * 8)];
            bf16x8 bk1 = *(const bf16x8*)&k_lds[krow * 64 + (((4 + quad) ^ (l15 & 7)) * 8)];
            f32x4 a = (f32x4){0.f, 0.f, 0.f, 0.f};
            a = __builtin_amdgcn_mfma_f32_16x16x32_bf16(aq0, bk0, a, 0, 0, 0);
            a = __builtin_amdgcn_mfma_f32_16x16x32_bf16(aq1, bk1, a, 0, 0, 0);
            s[ct] = a;
        }

        // online softmax (rows live on (quad, reg); cols on lane&15 x 4 ct)
        float mnew[4], alpha[4];
#pragma unroll
        for (int r = 0; r < 4; r++) {
            float mx = fmaxf(fmaxf(s[0][r], s[1][r]), fmaxf(s[2][r], s[3][r]));
            mx = fmaxf(mx, __shfl_xor(mx, 1));
            mx = fmaxf(mx, __shfl_xor(mx, 2));
            mx = fmaxf(mx, __shfl_xor(mx, 4));
            mx = fmaxf(mx, __shfl_xor(mx, 8));
            mnew[r] = fmaxf(m_r[r], mx);
            alpha[r] = exp2f((m_r[r] - mnew[r]) * LOG2E);
            m_r[r] = mnew[r];
        }
#pragma unroll
        for (int r = 0; r < 4; r++) {
            float sum = 0.f;
#pragma unroll
            for (int ct = 0; ct < 4; ct++) {
                float pv = exp2f((s[ct][r] - mnew[r]) * LOG2E);
                s[ct][r] = pv;
                sum += pv;
            }
            sum += __shfl_xor(sum, 1);
            sum += __shfl_xor(sum, 2);
            sum += __shfl_xor(sum, 4);
            sum += __shfl_xor(sum, 8);
            l_r[r] = l_r[r] * alpha[r] + sum;
        }
#pragma unroll
        for (int ctv = 0; ctv < 8; ctv++)
#pragma unroll
            for (int r = 0; r < 4; r++) acc_o[ctv][r] *= alpha[r];

        // P (C/D layout) -> LDS (row-major, swizzled) for A-operand reload
#pragma unroll
        for (int ct = 0; ct < 4; ct++)
#pragma unroll
            for (int r = 0; r < 4; r++) {
                int prow = quad * 4 + r;
                int col = ct * 16 + l15;
                int chk = ((col >> 3) ^ (prow & 7));
                p_lds[w * 1024 + prow * 64 + chk * 8 + (col & 7)] = f2bf(s[ct][r]);
            }
        __syncthreads();

        const bf16x8 ap0 = *(const bf16x8*)&p_lds[w * 1024 + l15 * 64 + (((quad) ^ (l15 & 7)) * 8)];
        const bf16x8 ap1 = *(const bf16x8*)&p_lds[w * 1024 + l15 * 64 + (((4 + quad) ^ (l15 & 7)) * 8)];
#pragma unroll
        for (int ctv = 0; ctv < 8; ctv++) {
            int vrow = ctv * 16 + l15;
            bf16x8 bv0 = *(const bf16x8*)&v_lds[vrow * 64 + (((quad) ^ (l15 & 7)) * 8)];
            bf16x8 bv1 = *(const bf16x8*)&v_lds[vrow * 64 + (((4 + quad) ^ (l15 & 7)) * 8)];
            acc_o[ctv] = __builtin_amdgcn_mfma_f32_16x16x32_bf16(ap0, bv0, acc_o[ctv], 0, 0, 0);
            acc_o[ctv] = __builtin_amdgcn_mfma_f32_16x16x32_bf16(ap1, bv1, acc_o[ctv], 0, 0, 0);
        }
    }

    // write partials (unnormalized O', m, l)
    const size_t base = (((size_t)n * NQT + qt) * NCHUNK + chunk) * 64;
#pragma unroll
    for (int ctv = 0; ctv < 8; ctv++)
#pragma unroll
        for (int r = 0; r < 4; r++) {
            int lrow = w * 16 + quad * 4 + r;
            o_part[(base + lrow) * 128 + ctv * 16 + l15] = acc_o[ctv][r];
        }
    if (l15 == 0) {
#pragma unroll
        for (int r = 0; r < 4; r++) {
            int lrow = w * 16 + quad * 4 + r;
            ml_part[base * 2 + lrow]      = m_r[r];
            ml_part[base * 2 + 64 + lrow] = l_r[r];
        }
    }
}

// ---------------------------------------------------------------------------
// Kernel 4: combine the NCHUNK partials, normalize, write out[n][c][p] fp32.
// ---------------------------------------------------------------------------
__global__ __launch_bounds__(256) void combine_kernel(
    const float* __restrict__ o_part, const float* __restrict__ ml,
    float* __restrict__ out) {
    const int t = threadIdx.x;
    const int gr = blockIdx.x * 2 + (t >> 7);   // global row in [0, 2*9216)
    const int c = t & 127;
    const int n = gr / HW_;
    const int p = gr - n * HW_;
    const int qt = p >> 6, r = p & 63;
    const size_t b0 = (((size_t)n * NQT + qt) * NCHUNK + 0) * 64;
    const size_t b1 = (((size_t)n * NQT + qt) * NCHUNK + 1) * 64;
    float m1 = ml[b0 * 2 + r], l1 = ml[b0 * 2 + 64 + r];
    float m2 = ml[b1 * 2 + r], l2 = ml[b1 * 2 + 64 + r];
    float ms = fmaxf(m1, m2);
    float e1 = exp2f((m1 - ms) * LOG2E);
    float e2 = exp2f((m2 - ms) * LOG2E);
    float o1 = o_part[(b0 + r) * 128 + c];
    float o2 = o_part[(b1 + r) * 128 + c];
    float denom = e1 * l1 + e2 * l2;
    out[((size_t)n * CC + c) * HW_ + p] = (e1 * o1 + e2 * o2) / denom;
}

// ---------------------------------------------------------------------------
// Workspace layout (bytes), all 16B aligned; total ~28.8 MB:
//   wt      @        0  : 131072      (128x256 fp32)
//   qb      @   131072  : 2359296     (2x9216x64 bf16)
//   kb      @  2490368  : 2359296
//   vtb     @  4849664  : 4718592     (2x128x9216 bf16)
//   o_part  @  9568256  : 18874368    (2x144x2x64x128 fp32)
//   ml      @ 28442624  : 294912      (2x144x2x2x64 fp32)
// ---------------------------------------------------------------------------
extern "C" void kernel_launch(void* const* d_in, const int* in_sizes, int n_in,
                              void* d_out, int out_size, void* d_ws, size_t ws_size,
                              hipStream_t stream) {
    const float* x  = (const float*)d_in[0];
    const float* w1 = (const float*)d_in[1];
    const float* b1 = (const float*)d_in[2];
    const float* a1 = (const float*)d_in[3];
    const float* w2 = (const float*)d_in[4];
    const float* b2 = (const float*)d_in[5];
    const float* a2 = (const float*)d_in[6];
    const float* wa = (const float*)d_in[7];
    const float* ba = (const float*)d_in[8];
    const float* aa = (const float*)d_in[9];
    float* out = (float*)d_out;

    char* ws = (char*)d_ws;
    float*          wt     = (float*)(ws + 0);
    unsigned short* qb     = (unsigned short*)(ws + 131072);
    unsigned short* kb     = (unsigned short*)(ws + 2490368);
    unsigned short* vtb    = (unsigned short*)(ws + 4849664);
    float*          o_part = (float*)(ws + 9568256);
    float*          ml     = (float*)(ws + 28442624);

    hipLaunchKernelGGL(prep_w, dim3(128), dim3(256), 0, stream, w1, w2, wa, wt);
    hipLaunchKernelGGL(conv_kernel, dim3(144, 4, 2), dim3(256), 0, stream,
                       x, wt, b1, a1, b2, a2, ba, aa, qb, kb, vtb);
    hipLaunchKernelGGL(attn_kernel, dim3(NQT, NCHUNK, 2), dim3(256), 0, stream,
                       qb, kb, vtb, o_part, ml);
    hipLaunchKernelGGL(combine_kernel, dim3(HW_), dim3(256), 0, stream,
                       o_part, ml, out);
}

// Round 2
// 254.700 us; speedup vs baseline: 1.6497x; 1.6497x over previous
//
#include <hip/hip_runtime.h>
#include <cstdint>
#include <cstddef>

// Problem constants (N=2, C=128, Ce=64, H=W=96)
#define HW_ 9216
#define CC 128
#define NQT 144      // HW/64 Q-tiles
#define LOG2E 1.44269504088896f

typedef short bf16x8 __attribute__((ext_vector_type(8)));
typedef unsigned short u16x4 __attribute__((ext_vector_type(4)));
typedef float f32x4 __attribute__((ext_vector_type(4)));

__device__ __forceinline__ unsigned short f2bf(float f) {
    unsigned int u = __builtin_bit_cast(unsigned int, f);
    u += 0x7FFFu + ((u >> 16) & 1u);   // RNE
    return (unsigned short)(u >> 16);
}

// ---------------------------------------------------------------------------
// Kernel 1: transpose weights into wt[c][o], o in [0,256): 0..63=w1, 64..127=w2,
// 128..255=wa.
// ---------------------------------------------------------------------------
__global__ __launch_bounds__(256) void prep_w(const float* __restrict__ w1,
                                              const float* __restrict__ w2,
                                              const float* __restrict__ wa,
                                              float* __restrict__ wt) {
    int idx = blockIdx.x * 256 + threadIdx.x;   // 32768 total
    int o = idx >> 7, c = idx & 127;
    float v;
    if (o < 64)       v = w1[o * 128 + c];
    else if (o < 128) v = w2[(o - 64) * 128 + c];
    else              v = wa[(o - 128) * 128 + c];
    wt[c * 256 + o] = v;
}

// ---------------------------------------------------------------------------
// Kernel 2: 1x1 conv + PReLU (fp32 accumulate), write bf16.
//   oset 0 -> Q[n][p][d] (pre-scaled by log2e; PReLU commutes with pos scale)
//   oset 1 -> K[n][p][d]
//   oset 2,3 -> Vt[n][c][p]
// ---------------------------------------------------------------------------
__global__ __launch_bounds__(256) void conv_kernel(
    const float* __restrict__ x, const float* __restrict__ wt,
    const float* __restrict__ b1, const float* __restrict__ a1,
    const float* __restrict__ b2, const float* __restrict__ a2,
    const float* __restrict__ ba, const float* __restrict__ aa,
    unsigned short* __restrict__ qb, unsigned short* __restrict__ kb,
    unsigned short* __restrict__ vtb) {
    const int ptile = blockIdx.x;   // 144
    const int oset  = blockIdx.y;   // 4
    const int n     = blockIdx.z;   // 2
    const int t = threadIdx.x;
    const int p = t & 63;
    const int og = __builtin_amdgcn_readfirstlane(t >> 6);
    const int p0 = ptile * 64;

    __shared__ float xs[128 * 64];
    for (int c = t >> 6; c < 128; c += 4)
        xs[c * 64 + p] = x[((size_t)n * CC + c) * HW_ + p0 + p];
    __syncthreads();

    const int obase = oset * 64 + og * 16;
    float acc[16];
#pragma unroll
    for (int i = 0; i < 16; i++) acc[i] = 0.f;

    for (int c = 0; c < 128; c++) {
        float xv = xs[c * 64 + p];
        const float* wr = wt + c * 256 + obase;   // uniform -> s_load
#pragma unroll
        for (int i = 0; i < 16; i++) acc[i] = fmaf(wr[i], xv, acc[i]);
    }

    const float* bias_p;
    const float* slope_p;
    if (oset == 0)      { bias_p = b1; slope_p = a1; }
    else if (oset == 1) { bias_p = b2; slope_p = a2; }
    else                { bias_p = ba; slope_p = aa; }
    const float slope = slope_p[0];

    unsigned short vals[16];
#pragma unroll
    for (int i = 0; i < 16; i++) {
        float bv = (oset < 2) ? bias_p[og * 16 + i] : bias_p[obase - 128 + i];
        float y = acc[i] + bv;
        y = (y >= 0.f) ? y : slope * y;
        if (oset == 0) y *= LOG2E;   // fold softmax's ln->log2 into Q
        vals[i] = f2bf(y);
    }

    if (oset < 2) {
        unsigned short* dst = (oset == 0 ? qb : kb) + ((size_t)n * HW_ + p0 + p) * 64 + og * 16;
        bf16x8 v0, v1;
#pragma unroll
        for (int i = 0; i < 8; i++) { v0[i] = (short)vals[i]; v1[i] = (short)vals[8 + i]; }
        *(bf16x8*)(dst)     = v0;
        *(bf16x8*)(dst + 8) = v1;
    } else {
        int c0 = obase - 128;
#pragma unroll
        for (int i = 0; i < 16; i++)
            vtb[((size_t)n * CC + c0 + i) * HW_ + p0 + p] = vals[i];
    }
}

// ---------------------------------------------------------------------------
// Kernel 3: flash attention, S^T formulation.
//   S^T = K·Q^T  (A=K, B=Q)  -> C/D: col = q = lane&15, row = j = quad*4+r
//   softmax: in-lane over 16 + 2 shfl_xor (quads); m,l scalar per lane
//   P^T -> per-wave LDS [q][j] via 4 ds_write_b64 (j-contig in 4s), no barrier
//   O^T = V^T·P^T (A=V^T, B=P^T) -> col = q, row = c-local
// Block = 4 waves x 16 q-rows = 64 q. KV chunked over blockIdx.y.
// ---------------------------------------------------------------------------
__global__ __launch_bounds__(256, 4) void attn_kernel(
    const unsigned short* __restrict__ qb, const unsigned short* __restrict__ kb,
    const unsigned short* __restrict__ vtb,
    float* __restrict__ o_part, float* __restrict__ ml_part,
    int nch, int chunk_j) {
    const int qt    = blockIdx.x;   // 144
    const int chunk = blockIdx.y;   // nch
    const int n     = blockIdx.z;   // 2
    const int t = threadIdx.x;
    const int w = t >> 6;
    const int lane = t & 63;
    const int l15 = lane & 15;
    const int quad = lane >> 4;
    const int e7 = l15 & 7;

    __shared__ __align__(16) unsigned short k_lds[64 * 64];     // [j][d] swizzled
    __shared__ __align__(16) unsigned short v_lds[128 * 64];    // [c][j] swizzled
    __shared__ __align__(16) unsigned short p_lds[4 * 16 * 64]; // per-wave [q][j] swizzled

    // Q B-fragments: B[k=d][n=q]: lane holds q=l15, d = quad*8.. contiguous
    const int row_g = qt * 64 + w * 16 + l15;
    const bf16x8 bq0 = *(const bf16x8*)(qb + ((size_t)n * HW_ + row_g) * 64 + quad * 8);
    const bf16x8 bq1 = *(const bf16x8*)(qb + ((size_t)n * HW_ + row_g) * 64 + 32 + quad * 8);

    f32x4 acc_o[8];
#pragma unroll
    for (int i = 0; i < 8; i++) acc_o[i] = (f32x4){0.f, 0.f, 0.f, 0.f};
    float m_s = -INFINITY, l_s = 0.f;

    const int stg_row = t >> 3, stg_seg = t & 7;
    const int iters = chunk_j / 64;
    int j0 = chunk * chunk_j;

    // software pipeline: prefetch tile 0 into VGPRs
    bf16x8 kr0, kr1, vr0, vr1, vr2, vr3;
    {
        const unsigned short* kp = kb + ((size_t)n * HW_ + j0 + stg_row) * 64 + stg_seg * 8;
        kr0 = *(const bf16x8*)kp;
        kr1 = *(const bf16x8*)(kp + 32 * 64);
        const unsigned short* vp = vtb + ((size_t)n * CC + stg_row) * HW_ + j0 + stg_seg * 8;
        vr0 = *(const bf16x8*)vp;
        vr1 = *(const bf16x8*)(vp + (size_t)32 * HW_);
        vr2 = *(const bf16x8*)(vp + (size_t)64 * HW_);
        vr3 = *(const bf16x8*)(vp + (size_t)96 * HW_);
    }

    for (int it = 0; it < iters; ++it, j0 += 64) {
        __syncthreads();   // previous iteration's k/v_lds reads complete
        {
            int r0 = stg_row, r1 = stg_row + 32;
            *(bf16x8*)&k_lds[r0 * 64 + ((stg_seg ^ (r0 & 7)) * 8)] = kr0;
            *(bf16x8*)&k_lds[r1 * 64 + ((stg_seg ^ (r1 & 7)) * 8)] = kr1;
            *(bf16x8*)&v_lds[r0 * 64 + ((stg_seg ^ (r0 & 7)) * 8)] = vr0;
            *(bf16x8*)&v_lds[r1 * 64 + ((stg_seg ^ (r1 & 7)) * 8)] = vr1;
            int r2 = stg_row + 64, r3 = stg_row + 96;
            *(bf16x8*)&v_lds[r2 * 64 + ((stg_seg ^ (r2 & 7)) * 8)] = vr2;
            *(bf16x8*)&v_lds[r3 * 64 + ((stg_seg ^ (r3 & 7)) * 8)] = vr3;
        }
        __syncthreads();

        if (it + 1 < iters) {   // issue next tile's loads; overlap with compute
            const unsigned short* kp = kb + ((size_t)n * HW_ + j0 + 64 + stg_row) * 64 + stg_seg * 8;
            kr0 = *(const bf16x8*)kp;
            kr1 = *(const bf16x8*)(kp + 32 * 64);
            const unsigned short* vp = vtb + ((size_t)n * CC + stg_row) * HW_ + j0 + 64 + stg_seg * 8;
            vr0 = *(const bf16x8*)vp;
            vr1 = *(const bf16x8*)(vp + (size_t)32 * HW_);
            vr2 = *(const bf16x8*)(vp + (size_t)64 * HW_);
            vr3 = *(const bf16x8*)(vp + (size_t)96 * HW_);
        }

        // S^T = K Q^T: 4 tiles along j (16 each)
        f32x4 s[4];
#pragma unroll
        for (int ct = 0; ct < 4; ct++) {
            int jr = ct * 16 + l15;
            bf16x8 ak0 = *(const bf16x8*)&k_lds[jr * 64 + ((quad ^ e7) * 8)];
            bf16x8 ak1 = *(const bf16x8*)&k_lds[jr * 64 + (((4 + quad) ^ e7) * 8)];
            f32x4 a = (f32x4){0.f, 0.f, 0.f, 0.f};
            a = __builtin_amdgcn_mfma_f32_16x16x32_bf16(ak0, bq0, a, 0, 0, 0);
            a = __builtin_amdgcn_mfma_f32_16x16x32_bf16(ak1, bq1, a, 0, 0, 0);
            s[ct] = a;
        }

        // online softmax: all 16 in-lane values share q = l15
        float smax = s[0][0];
#pragma unroll
        for (int ct = 0; ct < 4; ct++)
#pragma unroll
            for (int r = 0; r < 4; r++) smax = fmaxf(smax, s[ct][r]);
        smax = fmaxf(smax, __shfl_xor(smax, 16));
        smax = fmaxf(smax, __shfl_xor(smax, 32));
        float mnew = fmaxf(m_s, smax);
        float alpha = exp2f(m_s - mnew);
        m_s = mnew;

        float sum = 0.f;
#pragma unroll
        for (int ct = 0; ct < 4; ct++)
#pragma unroll
            for (int r = 0; r < 4; r++) {
                float pv = exp2f(s[ct][r] - mnew);
                s[ct][r] = pv;
                sum += pv;
            }
        sum += __shfl_xor(sum, 16);
        sum += __shfl_xor(sum, 32);
        l_s = l_s * alpha + sum;

#pragma unroll
        for (int i = 0; i < 8; i++) {
            acc_o[i][0] *= alpha; acc_o[i][1] *= alpha;
            acc_o[i][2] *= alpha; acc_o[i][3] *= alpha;
        }

        // P^T -> per-wave LDS [q][j]: j = 16ct + 4quad + r, 4 contiguous -> b64
#pragma unroll
        for (int ct = 0; ct < 4; ct++) {
            u16x4 pk;
            pk[0] = f2bf(s[ct][0]); pk[1] = f2bf(s[ct][1]);
            pk[2] = f2bf(s[ct][2]); pk[3] = f2bf(s[ct][3]);
            int chunkid = 2 * ct + (quad >> 1);
            int off = l15 * 64 + ((chunkid ^ e7) * 8) + 4 * (quad & 1);
            *(u16x4*)&p_lds[w * 1024 + off] = pk;
        }
        // same-wave readback: compiler inserts lgkmcnt wait; no barrier needed
        const bf16x8 bp0 = *(const bf16x8*)&p_lds[w * 1024 + l15 * 64 + ((quad ^ e7) * 8)];
        const bf16x8 bp1 = *(const bf16x8*)&p_lds[w * 1024 + l15 * 64 + (((4 + quad) ^ e7) * 8)];

        // O^T += V^T P^T
#pragma unroll
        for (int ctv = 0; ctv < 8; ctv++) {
            int cr = ctv * 16 + l15;
            bf16x8 av0 = *(const bf16x8*)&v_lds[cr * 64 + ((quad ^ e7) * 8)];
            bf16x8 av1 = *(const bf16x8*)&v_lds[cr * 64 + (((4 + quad) ^ e7) * 8)];
            acc_o[ctv] = __builtin_amdgcn_mfma_f32_16x16x32_bf16(av0, bp0, acc_o[ctv], 0, 0, 0);
            acc_o[ctv] = __builtin_amdgcn_mfma_f32_16x16x32_bf16(av1, bp1, acc_o[ctv], 0, 0, 0);
        }
    }

    // partials: O^T layout [c][q] — rows c = 16ctv+4quad+r, col q = w*16+l15
    const size_t cbase = ((size_t)(n * NQT + qt) * nch + chunk) * 128;
    const int qloc = w * 16 + l15;
#pragma unroll
    for (int ctv = 0; ctv < 8; ctv++)
#pragma unroll
        for (int r = 0; r < 4; r++) {
            int c = ctv * 16 + 4 * quad + r;
            o_part[(cbase + c) * 64 + qloc] = acc_o[ctv][r];
        }
    if (quad == 0) {   // m,l are quad-uniform per q
        size_t mlb = ((size_t)(n * NQT + qt) * nch + chunk) * 128;
        ml_part[mlb + qloc]      = m_s;
        ml_part[mlb + 64 + qloc] = l_s;
    }
}

// ---------------------------------------------------------------------------
// Kernel 4: combine nch partials, normalize, write out[n][c][p] fp32.
// ---------------------------------------------------------------------------
__global__ __launch_bounds__(256) void combine_kernel(
    const float* __restrict__ o_part, const float* __restrict__ ml,
    float* __restrict__ out, int nch) {
    int gid = blockIdx.x * 256 + threadIdx.x;
    int r = gid & 63;
    int rest = gid >> 6;
    int c = rest & 127;
    int nqt = rest >> 7;           // 0..287
    int n = nqt / NQT, qtp = nqt - n * NQT;

    float mv[4], lv[4];
    float ms = -INFINITY;
    for (int ch = 0; ch < nch; ch++) {
        size_t mlb = ((size_t)nqt * nch + ch) * 128;
        mv[ch] = ml[mlb + r];
        lv[ch] = ml[mlb + 64 + r];
        ms = fmaxf(ms, mv[ch]);
    }
    float num = 0.f, den = 0.f;
    for (int ch = 0; ch < nch; ch++) {
        float e = exp2f(mv[ch] - ms);
        num = fmaf(e, o_part[(((size_t)nqt * nch + ch) * 128 + c) * 64 + r], num);
        den = fmaf(e, lv[ch], den);
    }
    out[((size_t)n * CC + c) * HW_ + qtp * 64 + r] = num / den;
}

// ---------------------------------------------------------------------------
// Workspace layout (bytes):
//   wt 0 (131072) | qb 131072 (2359296) | kb 2490368 (2359296)
//   vtb 4849664 (4718592) | o_part 9568256 (nch*9437184) | ml after o_part
// nch=4 needs ~47.9 MB; falls back to nch=2 (28.7 MB, round-1-proven) if tight.
// ---------------------------------------------------------------------------
extern "C" void kernel_launch(void* const* d_in, const int* in_sizes, int n_in,
                              void* d_out, int out_size, void* d_ws, size_t ws_size,
                              hipStream_t stream) {
    const float* x  = (const float*)d_in[0];
    const float* w1 = (const float*)d_in[1];
    const float* b1 = (const float*)d_in[2];
    const float* a1 = (const float*)d_in[3];
    const float* w2 = (const float*)d_in[4];
    const float* b2 = (const float*)d_in[5];
    const float* a2 = (const float*)d_in[6];
    const float* wa = (const float*)d_in[7];
    const float* ba = (const float*)d_in[8];
    const float* aa = (const float*)d_in[9];
    float* out = (float*)d_out;

    const size_t need4 = 9568256 + 4ull * 9437184 + 4ull * 288 * 128 * 4;
    const int nch = (ws_size >= need4) ? 4 : 2;
    const int chunk_j = HW_ / nch;

    char* ws = (char*)d_ws;
    float*          wt     = (float*)(ws + 0);
    unsigned short* qb     = (unsigned short*)(ws + 131072);
    unsigned short* kb     = (unsigned short*)(ws + 2490368);
    unsigned short* vtb    = (unsigned short*)(ws + 4849664);
    float*          o_part = (float*)(ws + 9568256);
    float*          ml     = (float*)(ws + 9568256 + (size_t)nch * 9437184);

    hipLaunchKernelGGL(prep_w, dim3(128), dim3(256), 0, stream, w1, w2, wa, wt);
    hipLaunchKernelGGL(conv_kernel, dim3(144, 4, 2), dim3(256), 0, stream,
                       x, wt, b1, a1, b2, a2, ba, aa, qb, kb, vtb);
    hipLaunchKernelGGL(attn_kernel, dim3(NQT, nch, 2), dim3(256), 0, stream,
                       qb, kb, vtb, o_part, ml, nch, chunk_j);
    hipLaunchKernelGGL(combine_kernel, dim3(2 * NQT * 128 * 64 / 256), dim3(256), 0, stream,
                       o_part, ml, out, nch);
}